// Round 3
// baseline (245.178 us; speedup 1.0000x reference)
//
#include <hip/hip_runtime.h>
#include <stdint.h>

#define IN_F 1024
#define OUT_F 1024
#define SCALING 0.25f
#define BLOCK 256
#define NBLOCKS 512  // 2048 waves, all resident at ~230 VGPR (2 waves/SIMD)
#define NITER 8      // 16 rows per wave, 2 rows per inner iteration

// LoRA rank-4, persistent-wave streaming version.
//
// Every previous structure (R0 DMA+LDS, R1 per-row, R2 straight-line burst)
// landed at 80-87 us / ~2.4 TB/s because each wave's life was a chain of
// DEPENDENT memory round-trips; the scheduler sinks straight-line loads to
// their uses (R2 came back with VGPR=64), so "bursts" degenerate to
// load->wait->consume chains. Meanwhile fillBufferAligned hits 6.65 TB/s at
// 9% occupancy on this chip -> few waves saturate HBM iff issue is
// continuous.
//
// This version makes each wave independent (no LDS, no barriers) and
// software-pipelines across a LOOP: the next 2-row tile's 8 float4 loads are
// issued before computing the current tile. Loop-carried prefetch cannot be
// sunk to its use by the block scheduler, so every wave always has ~8 KB in
// flight. A (16 f4) and B (16 f4) fragments are loop-invariant registers.
// h is reduced with a full-wave butterfly so ALL lanes hold h -> phase 2
// (out = h@B^T) runs straight out of registers into coalesced stores.
__global__ __launch_bounds__(BLOCK, 2) void lora_stream(
    const float* __restrict__ x, const float* __restrict__ A,
    const float* __restrict__ B, float* __restrict__ out, int nrows) {
  const int lane = threadIdx.x & 63;
  const int gwave = (int)((blockIdx.x * BLOCK + threadIdx.x) >> 6);
  const int nwaves = (int)(gridDim.x * (BLOCK / 64));

  const float4* __restrict__ A4 = (const float4*)A;
  const float4* __restrict__ B4 = (const float4*)B;
  const float4* __restrict__ X4 = (const float4*)x;
  float4* __restrict__ out4 = (float4*)out;

  // a[r][k]: A row r, f4-col (lane + 64k). Loaded once; loop-invariant.
  float4 a[4][4];
#pragma unroll
  for (int r = 0; r < 4; ++r)
#pragma unroll
    for (int k = 0; k < 4; ++k) a[r][k] = A4[r * 256 + lane + 64 * k];

  // b[k][c]: B row 4*(lane+64k)+c — the rank-4 coeffs of output col
  // 4*(lane+64k)+c. 4 KB contiguous per (k) across the wave.
  float4 b[4][4];
#pragma unroll
  for (int k = 0; k < 4; ++k)
#pragma unroll
    for (int c = 0; c < 4; ++c) b[k][c] = B4[4 * (lane + 64 * k) + c];

  for (int grp = gwave; grp * 16 < nrows; grp += nwaves) {
    const int base = grp * 16;
    if (base + 16 <= nrows) {
      // ---- fast path: 16 full rows, 8 pipelined iterations of 2 rows ----
      float4 xr[2][8];  // [buf][row*4+k]; all indices static after unroll
#pragma unroll
      for (int j = 0; j < 2; ++j)
#pragma unroll
        for (int k = 0; k < 4; ++k)
          xr[0][j * 4 + k] = X4[(size_t)(base + j) * 256 + lane + 64 * k];

#pragma unroll
      for (int it = 0; it < NITER; ++it) {
        // Prefetch next tile FIRST — loop-carried, stays in flight under
        // this tile's compute + stores.
        if (it + 1 < NITER) {
#pragma unroll
          for (int j = 0; j < 2; ++j)
#pragma unroll
            for (int k = 0; k < 4; ++k)
              xr[(it + 1) & 1][j * 4 + k] =
                  X4[(size_t)(base + 2 * (it + 1) + j) * 256 + lane + 64 * k];
        }

        float p[2][4];
#pragma unroll
        for (int j = 0; j < 2; ++j)
#pragma unroll
          for (int r = 0; r < 4; ++r) p[j][r] = 0.f;

#pragma unroll
        for (int j = 0; j < 2; ++j)
#pragma unroll
          for (int k = 0; k < 4; ++k) {
            const float4 xv = xr[it & 1][j * 4 + k];
#pragma unroll
            for (int r = 0; r < 4; ++r)
              p[j][r] += xv.x * a[r][k].x + xv.y * a[r][k].y +
                         xv.z * a[r][k].z + xv.w * a[r][k].w;
          }

        // Full-wave butterfly: 8 independent values x 6 stages. All lanes
        // end with the complete row-sums (needed for phase 2 anyway).
#pragma unroll
        for (int off = 1; off < 64; off <<= 1)
#pragma unroll
          for (int j = 0; j < 2; ++j)
#pragma unroll
            for (int r = 0; r < 4; ++r)
              p[j][r] += __shfl_xor(p[j][r], off, 64);

#pragma unroll
        for (int j = 0; j < 2; ++j) {
          const float h0 = p[j][0] * SCALING;
          const float h1 = p[j][1] * SCALING;
          const float h2 = p[j][2] * SCALING;
          const float h3 = p[j][3] * SCALING;
          const size_t orow = (size_t)(base + 2 * it + j) * 256;
#pragma unroll
          for (int k = 0; k < 4; ++k) {
            float4 res;
            res.x = h0 * b[k][0].x + h1 * b[k][0].y + h2 * b[k][0].z +
                    h3 * b[k][0].w;
            res.y = h0 * b[k][1].x + h1 * b[k][1].y + h2 * b[k][1].z +
                    h3 * b[k][1].w;
            res.z = h0 * b[k][2].x + h1 * b[k][2].y + h2 * b[k][2].z +
                    h3 * b[k][2].w;
            res.w = h0 * b[k][3].x + h1 * b[k][3].y + h2 * b[k][3].z +
                    h3 * b[k][3].w;
            out4[orow + lane + 64 * k] = res;
          }
        }
      }
    } else {
      // ---- tail path: < 16 rows, simple per-row loop ----
      for (int row = base; row < nrows; ++row) {
        float q[4] = {0.f, 0.f, 0.f, 0.f};
#pragma unroll
        for (int k = 0; k < 4; ++k) {
          const float4 xv = X4[(size_t)row * 256 + lane + 64 * k];
#pragma unroll
          for (int r = 0; r < 4; ++r)
            q[r] += xv.x * a[r][k].x + xv.y * a[r][k].y + xv.z * a[r][k].z +
                    xv.w * a[r][k].w;
        }
#pragma unroll
        for (int off = 1; off < 64; off <<= 1)
#pragma unroll
          for (int r = 0; r < 4; ++r) q[r] += __shfl_xor(q[r], off, 64);
        const float h0 = q[0] * SCALING, h1 = q[1] * SCALING,
                    h2 = q[2] * SCALING, h3 = q[3] * SCALING;
#pragma unroll
        for (int k = 0; k < 4; ++k) {
          float4 res;
          res.x = h0 * b[k][0].x + h1 * b[k][0].y + h2 * b[k][0].z +
                  h3 * b[k][0].w;
          res.y = h0 * b[k][1].x + h1 * b[k][1].y + h2 * b[k][1].z +
                  h3 * b[k][1].w;
          res.z = h0 * b[k][2].x + h1 * b[k][2].y + h2 * b[k][2].z +
                  h3 * b[k][2].w;
          res.w = h0 * b[k][3].x + h1 * b[k][3].y + h2 * b[k][3].z +
                  h3 * b[k][3].w;
          out4[(size_t)row * 256 + lane + 64 * k] = res;
        }
      }
    }
  }
}

extern "C" void kernel_launch(void* const* d_in, const int* in_sizes, int n_in,
                              void* d_out, int out_size, void* d_ws,
                              size_t ws_size, hipStream_t stream) {
  const float* x = (const float*)d_in[0];
  const float* A = (const float*)d_in[1];
  const float* B = (const float*)d_in[2];
  float* out = (float*)d_out;

  const int nrows = in_sizes[0] / IN_F;  // 32768
  lora_stream<<<NBLOCKS, BLOCK, 0, stream>>>(x, A, B, out, nrows);
}

// Round 4
// 236.432 us; speedup vs baseline: 1.0370x; 1.0370x over previous
//
#include <hip/hip_runtime.h>
#include <stdint.h>

#define IN_F 1024
#define OUT_F 1024
#define SCALING 0.25f

typedef float f32x4 __attribute__((ext_vector_type(4)));

// Opaque-asm pin: compiler must keep v in VGPRs (cannot rematerialize the
// load through an asm that "modifies" the value). This is the direct fix for
// R1/R2/R3, where VGPR_Count (68/64/100) proved regalloc dropped the
// loop-invariant fragments and re-loaded them inside the hot loop.
#define PIN4(v) asm volatile("" : "+v"((v).x), "+v"((v).y), "+v"((v).z), "+v"((v).w))

// ---------------------------------------------------------------------------
// K1: h[row] = SCALING * (x[row,:] @ A^T)   — pure READ stream (134 MB in,
// 512 KB out). 1024 blocks x 256 thr = 4096 waves, 8 rows/wave, all resident
// at ~115 VGPR (16 waves/CU). Per iteration: prefetch next row's 4 float4
// (loop-carried), dot with pinned A-fragment, 6-stage butterfly, lane0
// writes h. No LDS, no barriers.
// ---------------------------------------------------------------------------
__global__ __launch_bounds__(256) void lora_h(
    const float* __restrict__ x, const float* __restrict__ A,
    float* __restrict__ h, int nrows) {
  const int lane = threadIdx.x & 63;
  const int gw = (int)((blockIdx.x * 256u + threadIdx.x) >> 6);
  const int row_base = gw * 8;
  if (row_base >= nrows) return;

  const float4* __restrict__ X4 = (const float4*)x;
  const float4* __restrict__ A4 = (const float4*)A;

  // a[r][k]: A row r, f4-col (lane + 64k). Pinned resident.
  float4 a[4][4];
#pragma unroll
  for (int r = 0; r < 4; ++r)
#pragma unroll
    for (int k = 0; k < 4; ++k) a[r][k] = A4[r * 256 + lane + 64 * k];
#pragma unroll
  for (int r = 0; r < 4; ++r)
#pragma unroll
    for (int k = 0; k < 4; ++k) PIN4(a[r][k]);

  float4 xr[2][4];
  {
    const size_t r0 = (size_t)row_base * 256;
#pragma unroll
    for (int k = 0; k < 4; ++k) xr[0][k] = X4[r0 + lane + 64 * k];
  }

  float4* __restrict__ h4 = (float4*)h;
#pragma unroll
  for (int it = 0; it < 8; ++it) {
    const int row = row_base + it;
    // Loop-carried prefetch first — stays in flight under this row's work.
    if (it + 1 < 8) {
      const int prow = min(row_base + it + 1, nrows - 1);  // safe clamp
      const size_t rp = (size_t)prow * 256;
#pragma unroll
      for (int k = 0; k < 4; ++k) xr[(it + 1) & 1][k] = X4[rp + lane + 64 * k];
    }
    if (row < nrows) {
      float p0 = 0.f, p1 = 0.f, p2 = 0.f, p3 = 0.f;
#pragma unroll
      for (int k = 0; k < 4; ++k) {
        const float4 xv = xr[it & 1][k];  // static index after unroll
        p0 += xv.x * a[0][k].x + xv.y * a[0][k].y + xv.z * a[0][k].z +
              xv.w * a[0][k].w;
        p1 += xv.x * a[1][k].x + xv.y * a[1][k].y + xv.z * a[1][k].z +
              xv.w * a[1][k].w;
        p2 += xv.x * a[2][k].x + xv.y * a[2][k].y + xv.z * a[2][k].z +
              xv.w * a[2][k].w;
        p3 += xv.x * a[3][k].x + xv.y * a[3][k].y + xv.z * a[3][k].z +
              xv.w * a[3][k].w;
      }
#pragma unroll
      for (int off = 1; off < 64; off <<= 1) {
        p0 += __shfl_xor(p0, off, 64);
        p1 += __shfl_xor(p1, off, 64);
        p2 += __shfl_xor(p2, off, 64);
        p3 += __shfl_xor(p3, off, 64);
      }
      if (lane == 0)
        h4[row] = make_float4(p0 * SCALING, p1 * SCALING, p2 * SCALING,
                              p3 * SCALING);
    }
  }
}

// ---------------------------------------------------------------------------
// K2: out[row][:] = h[row] @ B^T   — pure WRITE stream (134 MB out), shaped
// like fillBufferAligned (6.6 TB/s on this chip). Thread t owns output
// f4-col t -> needs only B rows 4t..4t+3 (16 regs, trivially resident).
// h tile (64 rows = 1 KB) broadcast from LDS. Nontemporal stores: out is
// never re-read, so don't thrash L3 with 134 MB of write-allocates (also
// preserves x's L3 residency for the next dispatch's K1).
// ---------------------------------------------------------------------------
__global__ __launch_bounds__(256) void lora_out(
    const float* __restrict__ h, const float* __restrict__ B,
    float* __restrict__ out, int nrows) {
  __shared__ float hs[64 * 4];
  const int t = threadIdx.x;
  const int base = blockIdx.x * 64;
  if (base >= nrows) return;

  const float4* __restrict__ B4 = (const float4*)B;
  const float4 b0 = B4[4 * t + 0];
  const float4 b1 = B4[4 * t + 1];
  const float4 b2 = B4[4 * t + 2];
  const float4 b3 = B4[4 * t + 3];

  const int tile = min(64, nrows - base);
  if (t < tile * 4) hs[t] = h[base * 4 + t];  // coalesced 1 KB
  __syncthreads();

  f32x4* __restrict__ out4 = (f32x4*)out;
  const float4* __restrict__ hv = (const float4*)hs;
#pragma unroll 4
  for (int r = 0; r < tile; ++r) {
    const float4 hh = hv[r];  // same addr all lanes -> LDS broadcast
    f32x4 res;
    res.x = hh.x * b0.x + hh.y * b0.y + hh.z * b0.z + hh.w * b0.w;
    res.y = hh.x * b1.x + hh.y * b1.y + hh.z * b1.z + hh.w * b1.w;
    res.z = hh.x * b2.x + hh.y * b2.y + hh.z * b2.z + hh.w * b2.w;
    res.w = hh.x * b3.x + hh.y * b3.y + hh.z * b3.z + hh.w * b3.w;
    __builtin_nontemporal_store(res, &out4[(size_t)(base + r) * 256 + t]);
  }
}

// ---------------------------------------------------------------------------
// Fallback (only if d_ws can't hold h): compact fused kernel, R3-style.
// ---------------------------------------------------------------------------
__global__ __launch_bounds__(256) void lora_fused(
    const float* __restrict__ x, const float* __restrict__ A,
    const float* __restrict__ B, float* __restrict__ out, int nrows) {
  const int lane = threadIdx.x & 63;
  const int gw = (int)((blockIdx.x * 256u + threadIdx.x) >> 6);
  const int row_base = gw * 4;
  if (row_base >= nrows) return;

  const float4* __restrict__ X4 = (const float4*)x;
  const float4* __restrict__ A4 = (const float4*)A;
  const float4* __restrict__ B4 = (const float4*)B;
  float4* __restrict__ out4 = (float4*)out;

  float4 a[4][4], b[4][4];
#pragma unroll
  for (int r = 0; r < 4; ++r)
#pragma unroll
    for (int k = 0; k < 4; ++k) a[r][k] = A4[r * 256 + lane + 64 * k];
#pragma unroll
  for (int k = 0; k < 4; ++k)
#pragma unroll
    for (int c = 0; c < 4; ++c) b[k][c] = B4[4 * (lane + 64 * k) + c];

  for (int it = 0; it < 4; ++it) {
    const int row = row_base + it;
    if (row >= nrows) break;
    float p0 = 0.f, p1 = 0.f, p2 = 0.f, p3 = 0.f;
#pragma unroll
    for (int k = 0; k < 4; ++k) {
      const float4 xv = X4[(size_t)row * 256 + lane + 64 * k];
      p0 += xv.x * a[0][k].x + xv.y * a[0][k].y + xv.z * a[0][k].z +
            xv.w * a[0][k].w;
      p1 += xv.x * a[1][k].x + xv.y * a[1][k].y + xv.z * a[1][k].z +
            xv.w * a[1][k].w;
      p2 += xv.x * a[2][k].x + xv.y * a[2][k].y + xv.z * a[2][k].z +
            xv.w * a[2][k].w;
      p3 += xv.x * a[3][k].x + xv.y * a[3][k].y + xv.z * a[3][k].z +
            xv.w * a[3][k].w;
    }
#pragma unroll
    for (int off = 1; off < 64; off <<= 1) {
      p0 += __shfl_xor(p0, off, 64);
      p1 += __shfl_xor(p1, off, 64);
      p2 += __shfl_xor(p2, off, 64);
      p3 += __shfl_xor(p3, off, 64);
    }
    const float h0 = p0 * SCALING, h1 = p1 * SCALING, h2 = p2 * SCALING,
                h3 = p3 * SCALING;
#pragma unroll
    for (int k = 0; k < 4; ++k) {
      float4 res;
      res.x = h0 * b[k][0].x + h1 * b[k][0].y + h2 * b[k][0].z + h3 * b[k][0].w;
      res.y = h0 * b[k][1].x + h1 * b[k][1].y + h2 * b[k][1].z + h3 * b[k][1].w;
      res.z = h0 * b[k][2].x + h1 * b[k][2].y + h2 * b[k][2].z + h3 * b[k][2].w;
      res.w = h0 * b[k][3].x + h1 * b[k][3].y + h2 * b[k][3].z + h3 * b[k][3].w;
      out4[(size_t)row * 256 + lane + 64 * k] = res;
    }
  }
}

extern "C" void kernel_launch(void* const* d_in, const int* in_sizes, int n_in,
                              void* d_out, int out_size, void* d_ws,
                              size_t ws_size, hipStream_t stream) {
  const float* x = (const float*)d_in[0];
  const float* A = (const float*)d_in[1];
  const float* B = (const float*)d_in[2];
  float* out = (float*)d_out;

  const int nrows = in_sizes[0] / IN_F;  // 32768
  const size_t h_bytes = (size_t)nrows * 4 * sizeof(float);  // 512 KB

  if (d_ws != nullptr && ws_size >= h_bytes) {
    float* h = (float*)d_ws;
    const int b1 = (nrows + 31) / 32;  // 8 rows/wave * 4 waves = 32/block
    lora_h<<<b1, 256, 0, stream>>>(x, A, h, nrows);
    const int b2 = (nrows + 63) / 64;
    lora_out<<<b2, 256, 0, stream>>>(h, B, out, nrows);
  } else {
    const int b = (nrows + 15) / 16;
    lora_fused<<<b, 256, 0, stream>>>(x, A, B, out, nrows);
  }
}